// Round 3
// baseline (124.137 us; speedup 1.0000x reference)
//
#include <hip/hip_runtime.h>
#include <math.h>

// Problem constants (fixed by setup_inputs)
#define N_TOTAL 2097152
#define NT 256              // threads per block
#define NC 16               // elements per thread (sequential chunk)
#define EPB (NT * NC)       // 4096 elements per block
#define NB (N_TOTAL / EPB)  // 512 blocks

// Projective map on homogeneous (x, g, 1):
//   x' = (al*x + be) / (ga*x + de)
//   g' = (e*x + c*g + f) / (ga*x + de)
// Matrix [[al,0,be],[e,c,f],[ga,0,de]] — closed under composition.
// All in DOUBLE: composites are near-parabolic with det ~ 1/T^2 (T up to 2e7)
// -> fp32 cancellation is marginal; fp64 has 1e9x headroom.
struct DMat { double al, be, ga, de, c, e, f; };

__device__ __forceinline__ DMat dmat_identity() {
    DMat m; m.al = 1.0; m.be = 0.0; m.ga = 0.0; m.de = 1.0; m.c = 1.0; m.e = 0.0; m.f = 0.0;
    return m;
}

// A applied AFTER B (matrix product A*B)
__device__ __forceinline__ DMat dmat_compose(const DMat& A, const DMat& B) {
    DMat r;
    r.al = A.al * B.al + A.be * B.ga;
    r.be = A.al * B.be + A.be * B.de;
    r.ga = A.ga * B.al + A.de * B.ga;
    r.de = A.ga * B.be + A.de * B.de;
    r.c  = A.c * B.c;
    r.e  = A.e * B.al + A.c * B.e + A.f * B.ga;
    r.f  = A.e * B.be + A.c * B.f + A.f * B.de;
    return r;
}

// Scale-invariant normalization; guarded so it can never manufacture NaN/Inf.
__device__ __forceinline__ void dmat_normalize(DMat& m) {
    double mx = fmax(fabs(m.al), fabs(m.be));
    mx = fmax(mx, fabs(m.ga));
    mx = fmax(mx, fabs(m.de));
    mx = fmax(mx, fabs(m.c));
    mx = fmax(mx, fabs(m.e));
    mx = fmax(mx, fabs(m.f));
    if (!(mx > 0.0) || isinf(mx)) return;   // all-zero or corrupt: leave as-is
    double inv = 1.0 / mx;
    m.al *= inv; m.be *= inv; m.ga *= inv; m.de *= inv;
    m.c *= inv; m.e *= inv; m.f *= inv;
}

__device__ __forceinline__ void dmat_store(double* sm, int i, const DMat& m) {
    sm[0 * NT + i] = m.al; sm[1 * NT + i] = m.be; sm[2 * NT + i] = m.ga;
    sm[3 * NT + i] = m.de; sm[4 * NT + i] = m.c;  sm[5 * NT + i] = m.e;
    sm[6 * NT + i] = m.f;
}

__device__ __forceinline__ DMat dmat_load(const double* sm, int i) {
    DMat m;
    m.al = sm[0 * NT + i]; m.be = sm[1 * NT + i]; m.ga = sm[2 * NT + i];
    m.de = sm[3 * NT + i]; m.c  = sm[4 * NT + i]; m.e  = sm[5 * NT + i];
    m.f  = sm[6 * NT + i];
    return m;
}

// Ordered inclusive Hillis-Steele scan across NT threads:
// at exit sm[i] = M_i * M_{i-1} * ... * M_0.
__device__ __forceinline__ DMat dmat_scan_inclusive(double* sm, DMat mine, int tid) {
    dmat_store(sm, tid, mine);
    __syncthreads();
    for (int d = 1; d < NT; d <<= 1) {
        DMat o;
        bool has = (tid >= d);
        if (has) o = dmat_load(sm, tid - d);
        __syncthreads();
        if (has) {
            mine = dmat_compose(mine, o);  // o is EARLIER -> right operand
            dmat_normalize(mine);
            dmat_store(sm, tid, mine);
        }
        __syncthreads();
    }
    return mine;
}

__device__ __forceinline__ DMat elem_mat(double P, double a, double U, double V, double yy) {
    double p = P * P;
    DMat m;
    m.al = p * (a - 2.0 * U * V);
    m.be = V * V;
    m.ga = -(p * U * U);
    m.de = a;
    m.c  = P * (a - U * V);
    m.e  = -(yy * p * U);
    m.f  = yy * V;
    return m;
}

// ---------------- Kernel 1: per-block inclusive composite ----------------
__global__ __launch_bounds__(NT) void k_upsweep(
    const float* __restrict__ t, const int* __restrict__ band,
    const float* __restrict__ y, const float* __restrict__ yerr,
    const float* __restrict__ lad, const float* __restrict__ lkp,
    double* __restrict__ block_comp)
{
    __shared__ double sm[7 * NT];
    const int tid = threadIdx.x;
    const double sigma2 = exp(2.0 * (double)lkp[0]);
    const double inv_ell = exp(-(double)lkp[1]);
    double amps[4];
    amps[0] = 1.0;
    amps[1] = exp((double)lad[0]);
    amps[2] = exp((double)lad[1]);
    amps[3] = exp((double)lad[2]);

    const int base = (blockIdx.x * NT + tid) * NC;
    double tprev = (base == 0) ? 0.0 : (double)t[base - 1];
    DMat acc = dmat_identity();
    #pragma unroll
    for (int k = 0; k < NC; k += 4) {
        float4 tv = *reinterpret_cast<const float4*>(t + base + k);
        float4 yv = *reinterpret_cast<const float4*>(y + base + k);
        float4 ev = *reinterpret_cast<const float4*>(yerr + base + k);
        int4   bv = *reinterpret_cast<const int4*>(band + base + k);
        float tc[4] = {tv.x, tv.y, tv.z, tv.w};
        float yc[4] = {yv.x, yv.y, yv.z, yv.w};
        float ec[4] = {ev.x, ev.y, ev.z, ev.w};
        int   bc[4] = {bv.x, bv.y, bv.z, bv.w};
        #pragma unroll
        for (int j = 0; j < 4; ++j) {
            double u = amps[bc[j] & 3];
            double a = (double)ec[j] * (double)ec[j] + sigma2 * u * u;
            double U = sigma2 * u;
            double P = ((base + k + j) == 0) ? 0.0
                     : exp(-((double)tc[j] - tprev) * inv_ell);
            acc = dmat_compose(elem_mat(P, a, U, u, (double)yc[j]), acc);
            tprev = (double)tc[j];
        }
    }
    dmat_normalize(acc);
    DMat incl = dmat_scan_inclusive(sm, acc, tid);
    if (tid == NT - 1) {
        double* o = block_comp + blockIdx.x * 7;
        o[0] = incl.al; o[1] = incl.be; o[2] = incl.ga; o[3] = incl.de;
        o[4] = incl.c;  o[5] = incl.e;  o[6] = incl.f;
    }
}

// ------ Kernel 2: spine scan -> per-block EXCLUSIVE composite matrix ------
__global__ __launch_bounds__(NT) void k_spine(
    const double* __restrict__ block_comp, double* __restrict__ block_excl)
{
    __shared__ double sm[7 * NT];
    const int tid = threadIdx.x;
    const double* p0 = block_comp + (2 * tid) * 7;
    const double* p1 = block_comp + (2 * tid + 1) * 7;
    DMat m0 = {p0[0], p0[1], p0[2], p0[3], p0[4], p0[5], p0[6]};
    DMat m1 = {p1[0], p1[1], p1[2], p1[3], p1[4], p1[5], p1[6]};
    DMat mine = dmat_compose(m1, m0);
    dmat_normalize(mine);
    dmat_scan_inclusive(sm, mine, tid);
    DMat E = (tid == 0) ? dmat_identity() : dmat_load(sm, tid - 1);
    double* o0 = block_excl + (2 * tid) * 7;
    o0[0] = E.al; o0[1] = E.be; o0[2] = E.ga; o0[3] = E.de;
    o0[4] = E.c;  o0[5] = E.e;  o0[6] = E.f;
    DMat M = dmat_compose(m0, E);
    dmat_normalize(M);
    double* o1 = block_excl + (2 * tid + 1) * 7;
    o1[0] = M.al; o1[1] = M.be; o1[2] = M.ga; o1[3] = M.de;
    o1[4] = M.c;  o1[5] = M.e;  o1[6] = M.f;
}

// ---------------- Kernel 3: replay with safe (0,0) evaluation -------------
__global__ __launch_bounds__(NT) void k_replay(
    const float* __restrict__ t, const int* __restrict__ band,
    const float* __restrict__ y, const float* __restrict__ yerr,
    const float* __restrict__ lad, const float* __restrict__ lkp,
    const double* __restrict__ block_excl, double* __restrict__ accum)
{
    __shared__ double sm[7 * NT];
    const int tid = threadIdx.x;
    const double sigma2 = exp(2.0 * (double)lkp[0]);
    const double inv_ell = exp(-(double)lkp[1]);
    double amps[4];
    amps[0] = 1.0;
    amps[1] = exp((double)lad[0]);
    amps[2] = exp((double)lad[1]);
    amps[3] = exp((double)lad[2]);

    const int base = (blockIdx.x * NT + tid) * NC;
    double tprev = (base == 0) ? 0.0 : (double)t[base - 1];

    double Pv[NC];
    float av[NC], Uv[NC], Vv[NC], yv_[NC];
    DMat acc = dmat_identity();
    #pragma unroll
    for (int k = 0; k < NC; k += 4) {
        float4 tv = *reinterpret_cast<const float4*>(t + base + k);
        float4 yv = *reinterpret_cast<const float4*>(y + base + k);
        float4 ev = *reinterpret_cast<const float4*>(yerr + base + k);
        int4   bv = *reinterpret_cast<const int4*>(band + base + k);
        float tc[4] = {tv.x, tv.y, tv.z, tv.w};
        float yc[4] = {yv.x, yv.y, yv.z, yv.w};
        float ec[4] = {ev.x, ev.y, ev.z, ev.w};
        int   bc[4] = {bv.x, bv.y, bv.z, bv.w};
        #pragma unroll
        for (int j = 0; j < 4; ++j) {
            double u = amps[bc[j] & 3];
            double a = (double)ec[j] * (double)ec[j] + sigma2 * u * u;
            double U = sigma2 * u;
            double P = ((base + k + j) == 0) ? 0.0
                     : exp(-((double)tc[j] - tprev) * inv_ell);
            Pv[k + j] = P;
            av[k + j] = (float)a; Uv[k + j] = (float)U;
            Vv[k + j] = (float)u; yv_[k + j] = yc[j];
            acc = dmat_compose(elem_mat(P, a, U, u, (double)yc[j]), acc);
            tprev = (double)tc[j];
        }
    }
    dmat_normalize(acc);
    dmat_scan_inclusive(sm, acc, tid);
    DMat E = (tid == 0) ? dmat_identity() : dmat_load(sm, tid - 1);

    // full-history exclusive composite for this thread = E_thread * E_block
    const double* pb = block_excl + blockIdx.x * 7;
    DMat Eb = {pb[0], pb[1], pb[2], pb[3], pb[4], pb[5], pb[6]};
    DMat F = dmat_compose(E, Eb);
    dmat_normalize(F);
    // apply at (x,g) = (0,0); x=0 is far from the repelling fixed point (~1)
    double x = 0.0, g = 0.0;
    if (F.de != 0.0 && !isinf(F.de)) {
        double invde = 1.0 / F.de;
        x = F.be * invde;
        g = F.f  * invde;
    }
    if (!isfinite(x)) x = 0.0;
    if (!isfinite(g)) g = 0.0;

    double s_logD = 0.0, s_quad = 0.0;
    #pragma unroll
    for (int k = 0; k < NC; ++k) {
        double P = Pv[k], a = (double)av[k], U = (double)Uv[k];
        double V = (double)Vv[k], yy = (double)yv_[k];
        double p = P * P;
        double S = p * x;
        double D = a - U * U * S;
        if (!(D > 1e-300)) D = 1e-300;  // NaN-proof; never triggers if math is right
        double W = (V - S * U) / D;
        double gn = P * g;
        double z = yy - U * gn;
        s_logD += log(D);
        s_quad += z * z / D;
        x = S + D * W * W;
        g = gn + W * z;
    }

    __syncthreads();
    sm[tid] = s_logD;
    sm[NT + tid] = s_quad;
    __syncthreads();
    for (int d = NT / 2; d > 0; d >>= 1) {
        if (tid < d) {
            sm[tid] += sm[tid + d];
            sm[NT + tid] += sm[NT + tid + d];
        }
        __syncthreads();
    }
    if (tid == 0) {
        atomicAdd(&accum[0], sm[0]);
        atomicAdd(&accum[1], sm[NT]);
    }
}

// --------------------- Kernel 0/4: zero + finalize ------------------------
__global__ void k_zero(double* __restrict__ accum) {
    accum[0] = 0.0;
    accum[1] = 0.0;
}

__global__ void k_final(const double* __restrict__ accum, float* __restrict__ out) {
    double r = -0.5 * (accum[0] + accum[1]
                       + (double)N_TOTAL * 1.8378770664093454836);  // log(2*pi)
    out[0] = (float)r;
}

extern "C" void kernel_launch(void* const* d_in, const int* in_sizes, int n_in,
                              void* d_out, int out_size, void* d_ws, size_t ws_size,
                              hipStream_t stream)
{
    const float* t    = (const float*)d_in[0];
    const int*   band = (const int*)d_in[1];
    const float* y    = (const float*)d_in[2];
    const float* yerr = (const float*)d_in[3];
    const float* lad  = (const float*)d_in[4];
    const float* lkp  = (const float*)d_in[5];

    double* dws        = (double*)d_ws;
    double* block_comp = dws;                 // NB * 7 doubles
    double* block_excl = dws + NB * 7;        // NB * 7 doubles
    double* accum      = dws + 2 * NB * 7;    // 2 doubles

    k_zero<<<1, 1, 0, stream>>>(accum);
    k_upsweep<<<NB, NT, 0, stream>>>(t, band, y, yerr, lad, lkp, block_comp);
    k_spine<<<1, NT, 0, stream>>>(block_comp, block_excl);
    k_replay<<<NB, NT, 0, stream>>>(t, band, y, yerr, lad, lkp, block_excl, accum);
    k_final<<<1, 1, 0, stream>>>(accum, (float*)d_out);
}